// Round 6
// baseline (1246.785 us; speedup 1.0000x reference)
//
#include <hip/hip_runtime.h>

// RecurrentDecoder: x_proj GEMM -> ONE fused persistent kernel:
//   blocks 0..63   = GRU scan. h exchanged as TAG-EMBEDDED f32 (2 mantissa
//                    LSBs = (t>>1)&3): the store IS the publication; consumers
//                    poll data tags directly (no flags on the critical path).
//                    Worker-frontier flags published only every 8 steps.
//   blocks 64..511 = dense-GEMM workers, LDS double-buffered global_load_lds
//                    pipeline with XOR-swizzled LDS (conflict-free ds_read).

typedef __attribute__((ext_vector_type(8))) short s16x8;  // 8 bf16 (4 VGPRs)
typedef __attribute__((ext_vector_type(4))) float f32x4;
typedef __attribute__((ext_vector_type(4))) int   i32x4;

#define B_      16
#define TSTEPS  255
#define H_      1024
#define G_      3072
#define E_      512
#define V_      32000
#define MROWS   4080   // B_*TSTEPS
#define MPAD    4096
#define NBLK_SCAN 64
#define NWORK     448
#define NBLK_TOT  512
#define NTILE_RB  32    // 4096/128
#define NTILE_CB  250   // 32000/128
#define FSTRIDE   16    // flags padded to 64B

__device__ __forceinline__ short f2bf(float f) {   // RNE f32 -> bf16 bits
  unsigned u = __float_as_uint(f);
  u = (u + 0x7fffu + ((u >> 16) & 1u)) >> 16;
  return (short)u;
}

__device__ __forceinline__ float frcp(float x) {
  float r;
  asm("v_rcp_f32 %0, %1" : "=v"(r) : "v"(x));
  return r;
}

__device__ __forceinline__ unsigned cvtpk(float lo, float hi) {  // 2xf32->bf16x2
  unsigned r;
  asm("v_cvt_pk_bf16_f32 %0, %1, %2" : "=v"(r) : "v"(lo), "v"(hi));
  return r;
}

// 16B load bypassing L1/L2 (sc0 sc1): reads meet write-through stores at L3
#define GLD_SC(dst, p)                                                         \
  asm volatile("global_load_dwordx4 %0, %1, off sc0 sc1"                       \
               : "=v"(dst) : "v"(p) : "memory")

// async global->LDS 16B: HW writes lane l at (wave-uniform) ldsbase + l*16
__device__ __forceinline__ void gload_lds16(const short* g, void* l) {
  __builtin_amdgcn_global_load_lds((const __attribute__((address_space(1))) void*)g,
                                   (__attribute__((address_space(3))) void*)l,
                                   16, 0, 0);
}

// ---------- prep kernels ----------

// src f32 [K][N] -> dst bf16 [N][K]
__global__ void transpose_cvt(const float* __restrict__ src, short* __restrict__ dst,
                              int K, int N) {
  __shared__ float tile[32][33];
  const int n0 = blockIdx.x * 32, k0 = blockIdx.y * 32;
  const int tx = threadIdx.x, ty0 = threadIdx.y;  // (32,8)
#pragma unroll
  for (int yy = 0; yy < 4; ++yy) {
    int ty = ty0 + yy * 8;
    tile[ty][tx] = src[(size_t)(k0 + ty) * N + (n0 + tx)];
  }
  __syncthreads();
#pragma unroll
  for (int yy = 0; yy < 4; ++yy) {
    int ty = ty0 + yy * 8;
    dst[(size_t)(n0 + ty) * K + (k0 + tx)] = f2bf(tile[tx][ty]);
  }
}

// true_outputs (16,256,512) f32 -> teacher A bf16 [4096][512], row = t*16+b
__global__ void pack_teacher(const float* __restrict__ src, short* __restrict__ dst) {
  int idx = blockIdx.x * 256 + threadIdx.x;  // 262144 total
  int row = idx >> 6;
  int c8 = (idx & 63) << 3;
  int t = row >> 4, b = row & 15;
  s16x8 v = {};
  if (t < TSTEPS) {
    const float* s = src + ((size_t)(b * 256 + t)) * E_ + c8;
#pragma unroll
    for (int j = 0; j < 8; ++j) v[j] = f2bf(s[j]);
  }
  *(s16x8*)(dst + (size_t)row * E_ + c8) = v;
}

// hb0 = tagged(latent, tag 0); hb1 = tag-3 poison (first matching t is 7,
// by which time h(3) has fully overwritten the buffer)
__global__ void init_h(const float* __restrict__ latent, float* __restrict__ hb) {
  int i = blockIdx.x * 256 + threadIdx.x;  // 16384
  unsigned u = __float_as_uint(latent[i]) & ~3u;
  ((unsigned*)hb)[i] = u;
  ((unsigned*)hb)[16384 + i] = 3u;
}

// ---------- plain GEMM (xproj only; dispatch-boundary coherence) ----------
__global__ __launch_bounds__(256) void gemm_bf16(
    const short* __restrict__ A, const short* __restrict__ BT,
    const float* __restrict__ bias, float* __restrict__ C, int N, int K) {
  const int tid = threadIdx.x;
  const int lane = tid & 63, w = tid >> 6;
  const int r = lane & 15, q = lane >> 4;
  const int bm = blockIdx.y * 128, bn = blockIdx.x * 128;
  const int wm = bm + (w >> 1) * 64, wn = bn + (w & 1) * 64;
  const short* Ab = A + (size_t)(wm + r) * K + q * 8;
  const short* Bb = BT + (size_t)(wn + r) * K + q * 8;
  f32x4 acc[4][4] = {};
  s16x8 a0[4], b0[4], a1[4], b1[4];
  const int nk = K >> 5;
#define GL(AA, BB, kk)                                                         \
  {                                                                            \
    _Pragma("unroll") for (int i = 0; i < 4; ++i) {                            \
      AA[i] = *(const s16x8*)(Ab + (size_t)i * 16 * K + (kk) * 32);            \
    }                                                                          \
    _Pragma("unroll") for (int j = 0; j < 4; ++j) {                            \
      BB[j] = *(const s16x8*)(Bb + (size_t)j * 16 * K + (kk) * 32);            \
    }                                                                          \
  }
#define MM(AA, BB)                                                             \
  {                                                                            \
    _Pragma("unroll") for (int i = 0; i < 4; ++i)                              \
        _Pragma("unroll") for (int j = 0; j < 4; ++j)                          \
            acc[i][j] = __builtin_amdgcn_mfma_f32_16x16x32_bf16(               \
                AA[i], BB[j], acc[i][j], 0, 0, 0);                             \
  }
  GL(a0, b0, 0)
#pragma unroll 1
  for (int ks = 0; ks < nk; ks += 2) {
    GL(a1, b1, ks + 1)
    MM(a0, b0)
    if (ks + 2 < nk) GL(a0, b0, ks + 2)
    MM(a1, b1)
  }
#undef GL
#undef MM
#pragma unroll
  for (int j = 0; j < 4; ++j) {
    const int col = wn + j * 16 + r;
    const float bv = bias[col];
#pragma unroll
    for (int i = 0; i < 4; ++i) {
#pragma unroll
      for (int rr = 0; rr < 4; ++rr) {
        const int row = wm + i * 16 + q * 4 + rr;
        C[(size_t)row * N + col] = acc[i][j][rr] + bv;
      }
    }
  }
}

// ---------- fused persistent scan + dense GEMM ----------
// sync[c*16]: per-scan-WG flag, published every 8 steps (t=7,15,..,247) and
// 256 at end; flag>=f => gruout rows of steps < f visible at L3.
__global__ __launch_bounds__(256, 2) void fused_scan_gemm(
    const short* __restrict__ WrecT,   // [3072][1024] bf16
    const float* __restrict__ xproj,   // [4096][3072] f32 rows t*16+m
    const float* __restrict__ bias1,   // recurrent bias [3072]
    float* __restrict__ hbuf,          // [2][16][1024] tagged f32 ping-pong
    short* __restrict__ gruout,        // [4096][1024] bf16 rows t*16+m
    const short* __restrict__ DwT,     // [32000][1024] bf16
    const float* __restrict__ db,      // [32000]
    float* __restrict__ out,           // [16*255][32000]
    unsigned* __restrict__ sync) {
  const int tid = threadIdx.x, lane = tid & 63, w = tid >> 6;
  const int r = lane & 15, q = lane >> 4;
  __shared__ s16x8 smem_v[2048];       // 32 KiB, shared between roles

  if (blockIdx.x < NBLK_SCAN) {
    // ================= scan role =================
    __builtin_amdgcn_s_setprio(3);
    typedef float RedT[4][3][64][4];   // 12 KiB each, double-buffered
    RedT* red = (RedT*)smem_v;
    const int c = blockIdx.x;
    s16x8 wb[3][8];
#pragma unroll
    for (int g = 0; g < 3; ++g)
#pragma unroll
      for (int s = 0; s < 8; ++s)
        wb[g][s] = *(const s16x8*)(WrecT + (size_t)(g * 1024 + c * 16 + r) * 1024 +
                                   (w * 8 + s) * 32 + q * 8);

    const int m = tid >> 4, nl = tid & 15, col = c * 16 + nl;
    const float bz = bias1[col], brr = bias1[1024 + col], bhh = bias1[2048 + col];
    const float* xb = xproj + (size_t)m * G_;   // row t*16+m => base + t*16*G_
    float* hb0 = hbuf;
    float* hb1 = hbuf + 16 * 1024;
    float h = 0.f;  // established from tagged hb0 at t=0 via the data path
    {   // local h init: read own latent-tagged value (tag 0, already at L3)
      h = hb0[m * 1024 + col];
    }
    float xz = xb[col], xr = xb[1024 + col], xh = xb[2048 + col];

    for (int t = 0; t < TSTEPS; ++t) {
      const float* hcur = (t & 1) ? hb1 : hb0;
      float* hnxt = (t & 1) ? hb0 : hb1;
      const int tg = (t >> 1) & 3;
      const float* lb = hcur + r * 1024 + w * 256 + q * 8;
      i32x4 va[16];
      for (;;) {   // data-tag poll: load fragment, accept when all tags match
#pragma unroll
        for (int s = 0; s < 8; ++s) {
          GLD_SC(va[2 * s], lb + s * 32);
          GLD_SC(va[2 * s + 1], lb + s * 32 + 4);
        }
        asm volatile("s_waitcnt vmcnt(0)" ::: "memory");
        __builtin_amdgcn_sched_barrier(0);
        unsigned bad = 0;
#pragma unroll
        for (int k2 = 0; k2 < 16; ++k2) {
          bad |= (unsigned)(va[k2][0] ^ tg) | (unsigned)(va[k2][1] ^ tg) |
                 (unsigned)(va[k2][2] ^ tg) | (unsigned)(va[k2][3] ^ tg);
        }
        if (__all((bad & 3u) == 0u)) break;
        __builtin_amdgcn_s_sleep(1);
      }
      // f32 -> bf16 fragments in-register
      s16x8 af[8];
#pragma unroll
      for (int s = 0; s < 8; ++s) {
        union { unsigned u[4]; s16x8 v; } pk;
        pk.u[0] = cvtpk(__int_as_float(va[2*s][0]), __int_as_float(va[2*s][1]));
        pk.u[1] = cvtpk(__int_as_float(va[2*s][2]), __int_as_float(va[2*s][3]));
        pk.u[2] = cvtpk(__int_as_float(va[2*s+1][0]), __int_as_float(va[2*s+1][1]));
        pk.u[3] = cvtpk(__int_as_float(va[2*s+1][2]), __int_as_float(va[2*s+1][3]));
        af[s] = pk.v;
      }
      f32x4 acc[3] = {};
#pragma unroll
      for (int s = 0; s < 8; ++s) {
        acc[0] = __builtin_amdgcn_mfma_f32_16x16x32_bf16(af[s], wb[0][s], acc[0], 0, 0, 0);
        acc[1] = __builtin_amdgcn_mfma_f32_16x16x32_bf16(af[s], wb[1][s], acc[1], 0, 0, 0);
        acc[2] = __builtin_amdgcn_mfma_f32_16x16x32_bf16(af[s], wb[2][s], acc[2], 0, 0, 0);
      }
      *(f32x4*)&red[t & 1][w][0][lane][0] = acc[0];
      *(f32x4*)&red[t & 1][w][1][lane][0] = acc[1];
      *(f32x4*)&red[t & 1][w][2][lane][0] = acc[2];
      __syncthreads();   // the ONLY per-step barrier
      const int rl = (m >> 2) * 16 + nl, ri = m & 3;
      float rz = bz, rr2 = brr, rh = bhh;
#pragma unroll
      for (int ww = 0; ww < 4; ++ww) {
        rz += red[t & 1][ww][0][rl][ri];
        rr2 += red[t & 1][ww][1][rl][ri];
        rh += red[t & 1][ww][2][rl][ri];
      }
      const float z = frcp(1.f + __expf(-(xz + rz)));
      const float rg = frcp(1.f + __expf(-(xr + rr2)));
      const float hh = tanhf(xh + rg * rh);
      h = z * h + (1.f - z) * hh;   // h stays f32 locally
      // publish h(t+1): tagged f32 store IS the publication
      const unsigned ntg = (unsigned)(((t + 1) >> 1) & 3);
      const unsigned hu = (__float_as_uint(h) & ~3u) | ntg;
      __hip_atomic_store((unsigned*)hnxt + (m * 1024 + col), hu,
                         __ATOMIC_RELAXED, __HIP_MEMORY_SCOPE_AGENT);
      // gruout (bf16-packed), off critical path
      const unsigned hb16 = (unsigned short)f2bf(h);
      const unsigned nb = __shfl(hb16, lane | 1, 64);
      const unsigned pv = hb16 | (nb << 16);
      if (!(tid & 1))
        __hip_atomic_store((unsigned*)gruout + (((size_t)(t * 16 + m)) * 1024 + col) / 2,
                           pv, __ATOMIC_RELAXED, __HIP_MEMORY_SCOPE_AGENT);
      if ((t & 7) == 7) {  // worker-frontier flag, 1-in-8 steps
        asm volatile("s_waitcnt vmcnt(0)" ::: "memory");
        __syncthreads();
        if (tid == 0)
          __hip_atomic_store(&sync[c * FSTRIDE], (unsigned)(t + 1),
                             __ATOMIC_RELAXED, __HIP_MEMORY_SCOPE_AGENT);
      }
      {  // prefetch next step's x slice (pad rows exist: zero teacher)
        const float* xn = xb + (size_t)(t + 1) * 16 * G_;
        xz = xn[col]; xr = xn[1024 + col]; xh = xn[2048 + col];
      }
    }
    // epilogue: final gruout visibility, flag -> 256
    asm volatile("s_waitcnt vmcnt(0)" ::: "memory");
    __syncthreads();
    if (tid == 0)
      __hip_atomic_store(&sync[c * FSTRIDE], 256u,
                         __ATOMIC_RELAXED, __HIP_MEMORY_SCOPE_AGENT);
  } else {
    // ================= dense GEMM worker role =================
    // LDS: buf{0,1} x (A[128][32] | B[128][32]) bf16, XOR-swizzled 16B slots.
    char* sb = (char*)smem_v;
    const int wr = w >> 1, wc = w & 1;
    const int xterm = ((q ^ ((r >> 1) & 3)) << 4);  // swizzled slot, bytes
    const int swz8 = (((lane & 3) ^ ((lane >> 3) & 3)) << 3);  // src col, elems
    const int j = blockIdx.x - NBLK_SCAN;  // 0..447
#pragma unroll 1
    for (int tq = j; tq < NTILE_RB * NTILE_CB; tq += NWORK) {
      const int rb = tq / NTILE_CB, cb = tq - rb * NTILE_CB;
      const unsigned need = (unsigned)(rb < 31 ? 8 * rb + 8 : 256);
      unsigned v = __hip_atomic_load(&sync[lane * FSTRIDE], __ATOMIC_RELAXED,
                                     __HIP_MEMORY_SCOPE_AGENT);
      while (!__all(v >= need)) {
        __builtin_amdgcn_s_sleep(32);
        v = __hip_atomic_load(&sync[lane * FSTRIDE], __ATOMIC_RELAXED,
                              __HIP_MEMORY_SCOPE_AGENT);
      }
      const short* Ag = gruout + (size_t)rb * 128 * 1024;  // cached: coherent
      const short* Bg = DwT + (size_t)cb * 128 * 1024;
      f32x4 acc[4][4] = {};
#define STAGE(buf, kk)                                                         \
  {                                                                            \
    _Pragma("unroll") for (int it = 0; it < 2; ++it) {                         \
      const size_t go = (size_t)(w * 32 + it * 16 + (lane >> 2)) * 1024 +      \
                        (kk) * 32 + swz8;                                      \
      char* lb2 = sb + (buf) * 16384 + w * 2048 + it * 1024;                   \
      gload_lds16(Ag + go, lb2);                                               \
      gload_lds16(Bg + go, lb2 + 8192);                                        \
    }                                                                          \
  }
      STAGE(0, 0)
#pragma unroll 1
      for (int kk = 0; kk < 32; ++kk) {
        __syncthreads();             // staged kk visible; prev buf reads done
        if (kk < 31) STAGE((kk + 1) & 1, kk + 1)
        const char* ab = sb + (kk & 1) * 16384;
        s16x8 af[4], bf[4];
#pragma unroll
        for (int i = 0; i < 4; ++i)
          af[i] = *(const s16x8*)(ab + (wr * 64 + i * 16 + r) * 64 + xterm);
#pragma unroll
        for (int j5 = 0; j5 < 4; ++j5)
          bf[j5] = *(const s16x8*)(ab + 8192 + (wc * 64 + j5 * 16 + r) * 64 + xterm);
#pragma unroll
        for (int i = 0; i < 4; ++i)
#pragma unroll
          for (int j5 = 0; j5 < 4; ++j5)
            acc[i][j5] = __builtin_amdgcn_mfma_f32_16x16x32_bf16(
                af[i], bf[j5], acc[i][j5], 0, 0, 0);
      }
#undef STAGE
      const int wm = rb * 128 + wr * 64, wn = cb * 128 + wc * 64;
#pragma unroll
      for (int j2 = 0; j2 < 4; ++j2) {
        const int col = wn + j2 * 16 + r;
        const float bv = db[col];
#pragma unroll
        for (int i = 0; i < 4; ++i) {
#pragma unroll
          for (int rr = 0; rr < 4; ++rr) {
            const int arow = wm + i * 16 + q * 4 + rr;
            const int t = arow >> 4, mm = arow & 15;
            if (t < TSTEPS)
              __builtin_nontemporal_store(
                  acc[i][j2][rr] + bv,
                  &out[(size_t)(mm * TSTEPS + t) * V_ + col]);
          }
        }
      }
      __syncthreads();  // LDS WAR: next tile's STAGE(0,0) vs this tile's reads
    }
  }
}

// ---------- launch ----------
extern "C" void kernel_launch(void* const* d_in, const int* in_sizes, int n_in,
                              void* d_out, int out_size, void* d_ws, size_t ws_size,
                              hipStream_t stream) {
  const float* latent = (const float*)d_in[0];
  const float* trueo  = (const float*)d_in[1];
  const float* gk     = (const float*)d_in[2];
  const float* grk    = (const float*)d_in[3];
  const float* gbias  = (const float*)d_in[4];
  const float* dw     = (const float*)d_in[5];
  const float* db     = (const float*)d_in[6];
  float* out = (float*)d_out;
  char* ws = (char*)d_ws;
  short*    WrecT  = (short*)(ws + 0);          //  6,291,456  [3072][1024] bf16
  short*    GkT    = (short*)(ws + 6291456);    //  3,145,728  [3072][512]  bf16
  short*    DwT    = (short*)(ws + 9437184);    // 65,536,000  [32000][1024] bf16
  short*    teachA = (short*)(ws + 74973184);   //  4,194,304  [4096][512]  bf16 rows t*16+b
  float*    hbuf   = (float*)(ws + 74973184);   //    131,072  [2][16][1024] tagged f32
                                                //  (aliases teachA: init_h runs AFTER
                                                //   the xproj GEMM consumed teachA;
                                                //   pack_teacher rewrites it each call)
  float*    xproj  = (float*)(ws + 79167488);   // 50,331,648  [4096][3072] f32 rows t*16+m
  short*    gruout = (short*)(ws + 129499136);  //  8,388,608  [4096][1024] bf16 rows t*16+m
  unsigned* syncb  = (unsigned*)(ws + 137953280); //    8,192  flags[64*16]

  hipMemsetAsync(syncb, 0, 8192, stream);
  transpose_cvt<<<dim3(96, 32), dim3(32, 8), 0, stream>>>(grk, WrecT, 1024, 3072);
  transpose_cvt<<<dim3(96, 16), dim3(32, 8), 0, stream>>>(gk, GkT, 512, 3072);
  transpose_cvt<<<dim3(1000, 32), dim3(32, 8), 0, stream>>>(dw, DwT, 1024, 32000);
  pack_teacher<<<1024, 256, 0, stream>>>(trueo, teachA);
  gemm_bf16<<<dim3(24, 32), 256, 0, stream>>>(teachA, GkT, gbias, xproj, G_, E_);
  init_h<<<64, 256, 0, stream>>>(latent, hbuf);   // after xproj GEMM (aliasing)
  fused_scan_gemm<<<NBLK_TOT, 256, 0, stream>>>(WrecT, xproj, gbias + G_, hbuf,
                                                gruout, DwT, db, out, syncb);
}

// Round 8
// 1243.624 us; speedup vs baseline: 1.0025x; 1.0025x over previous
//
#include <hip/hip_runtime.h>

// RecurrentDecoder: x_proj GEMM -> ONE fused persistent kernel:
//   blocks 0..63   = GRU scan. h exchanged as TAG-EMBEDDED f32 (2 mantissa
//                    LSBs = (t>>1)&3): the store IS the publication. Consumers
//                    poll a CHEAP 4-dword sample per producer (16B/lane), then
//                    load fragments once and verify per-dword tags (safety
//                    net). No flags / drains on the critical path.
//   blocks 64..511 = dense-GEMM workers, LDS double-buffered global_load_lds
//                    pipeline with XOR-swizzled LDS (conflict-free ds_read),
//                    nt stores for logits. Frontier flags every 8 steps.

typedef __attribute__((ext_vector_type(8))) short s16x8;  // 8 bf16 (4 VGPRs)
typedef __attribute__((ext_vector_type(4))) float f32x4;
typedef __attribute__((ext_vector_type(4))) int   i32x4;

#define B_      16
#define TSTEPS  255
#define H_      1024
#define G_      3072
#define E_      512
#define V_      32000
#define MROWS   4080   // B_*TSTEPS
#define MPAD    4096
#define NBLK_SCAN 64
#define NWORK     448
#define NBLK_TOT  512
#define NTILE_RB  32    // 4096/128
#define NTILE_CB  250   // 32000/128
#define FSTRIDE   16    // flags padded to 64B

__device__ __forceinline__ short f2bf(float f) {   // RNE f32 -> bf16 bits
  unsigned u = __float_as_uint(f);
  u = (u + 0x7fffu + ((u >> 16) & 1u)) >> 16;
  return (short)u;
}

__device__ __forceinline__ float frcp(float x) {
  float r;
  asm("v_rcp_f32 %0, %1" : "=v"(r) : "v"(x));
  return r;
}

__device__ __forceinline__ unsigned cvtpk(float lo, float hi) {  // 2xf32->bf16x2
  unsigned r;
  asm("v_cvt_pk_bf16_f32 %0, %1, %2" : "=v"(r) : "v"(lo), "v"(hi));
  return r;
}

// 16B load bypassing L1/L2 (sc0 sc1): reads meet write-through stores at L3
#define GLD_SC(dst, p)                                                         \
  asm volatile("global_load_dwordx4 %0, %1, off sc0 sc1"                       \
               : "=v"(dst) : "v"(p) : "memory")

// async global->LDS 16B: HW writes lane l at (wave-uniform) ldsbase + l*16
__device__ __forceinline__ void gload_lds16(const short* g, void* l) {
  __builtin_amdgcn_global_load_lds((const __attribute__((address_space(1))) void*)g,
                                   (__attribute__((address_space(3))) void*)l,
                                   16, 0, 0);
}

// ---------- prep kernels ----------

// src f32 [K][N] -> dst bf16 [N][K]
__global__ void transpose_cvt(const float* __restrict__ src, short* __restrict__ dst,
                              int K, int N) {
  __shared__ float tile[32][33];
  const int n0 = blockIdx.x * 32, k0 = blockIdx.y * 32;
  const int tx = threadIdx.x, ty0 = threadIdx.y;  // (32,8)
#pragma unroll
  for (int yy = 0; yy < 4; ++yy) {
    int ty = ty0 + yy * 8;
    tile[ty][tx] = src[(size_t)(k0 + ty) * N + (n0 + tx)];
  }
  __syncthreads();
#pragma unroll
  for (int yy = 0; yy < 4; ++yy) {
    int ty = ty0 + yy * 8;
    dst[(size_t)(n0 + ty) * K + (k0 + tx)] = f2bf(tile[tx][ty]);
  }
}

// true_outputs (16,256,512) f32 -> teacher A bf16 [4096][512], row = t*16+b
__global__ void pack_teacher(const float* __restrict__ src, short* __restrict__ dst) {
  int idx = blockIdx.x * 256 + threadIdx.x;  // 262144 total
  int row = idx >> 6;
  int c8 = (idx & 63) << 3;
  int t = row >> 4, b = row & 15;
  s16x8 v = {};
  if (t < TSTEPS) {
    const float* s = src + ((size_t)(b * 256 + t)) * E_ + c8;
#pragma unroll
    for (int j = 0; j < 8; ++j) v[j] = f2bf(s[j]);
  }
  *(s16x8*)(dst + (size_t)row * E_ + c8) = v;
}

// hb0 = tagged(latent, tag 0); hb1 = tag-3 poison
__global__ void init_h(const float* __restrict__ latent, float* __restrict__ hb) {
  int i = blockIdx.x * 256 + threadIdx.x;  // 16384
  unsigned u = __float_as_uint(latent[i]) & ~3u;
  ((unsigned*)hb)[i] = u;
  ((unsigned*)hb)[16384 + i] = 3u;
}

// ---------- plain GEMM (xproj only; dispatch-boundary coherence) ----------
__global__ __launch_bounds__(256) void gemm_bf16(
    const short* __restrict__ A, const short* __restrict__ BT,
    const float* __restrict__ bias, float* __restrict__ C, int N, int K) {
  const int tid = threadIdx.x;
  const int lane = tid & 63, w = tid >> 6;
  const int r = lane & 15, q = lane >> 4;
  const int bm = blockIdx.y * 128, bn = blockIdx.x * 128;
  const int wm = bm + (w >> 1) * 64, wn = bn + (w & 1) * 64;
  const short* Ab = A + (size_t)(wm + r) * K + q * 8;
  const short* Bb = BT + (size_t)(wn + r) * K + q * 8;
  f32x4 acc[4][4] = {};
  s16x8 a0[4], b0[4], a1[4], b1[4];
  const int nk = K >> 5;
#define GL(AA, BB, kk)                                                         \
  {                                                                            \
    _Pragma("unroll") for (int i = 0; i < 4; ++i) {                            \
      AA[i] = *(const s16x8*)(Ab + (size_t)i * 16 * K + (kk) * 32);            \
    }                                                                          \
    _Pragma("unroll") for (int j = 0; j < 4; ++j) {                            \
      BB[j] = *(const s16x8*)(Bb + (size_t)j * 16 * K + (kk) * 32);            \
    }                                                                          \
  }
#define MM(AA, BB)                                                             \
  {                                                                            \
    _Pragma("unroll") for (int i = 0; i < 4; ++i)                              \
        _Pragma("unroll") for (int j = 0; j < 4; ++j)                          \
            acc[i][j] = __builtin_amdgcn_mfma_f32_16x16x32_bf16(               \
                AA[i], BB[j], acc[i][j], 0, 0, 0);                             \
  }
  GL(a0, b0, 0)
#pragma unroll 1
  for (int ks = 0; ks < nk; ks += 2) {
    GL(a1, b1, ks + 1)
    MM(a0, b0)
    if (ks + 2 < nk) GL(a0, b0, ks + 2)
    MM(a1, b1)
  }
#undef GL
#undef MM
#pragma unroll
  for (int j = 0; j < 4; ++j) {
    const int col = wn + j * 16 + r;
    const float bv = bias[col];
#pragma unroll
    for (int i = 0; i < 4; ++i) {
#pragma unroll
      for (int rr = 0; rr < 4; ++rr) {
        const int row = wm + i * 16 + q * 4 + rr;
        C[(size_t)row * N + col] = acc[i][j][rr] + bv;
      }
    }
  }
}

// ---------- fused persistent scan + dense GEMM ----------
// sync[c*16]: per-scan-WG frontier flag, published every 8 steps and 256 at
// end; flag>=f => gruout rows of steps < f visible at L3.
__global__ __launch_bounds__(256, 2) void fused_scan_gemm(
    const short* __restrict__ WrecT,   // [3072][1024] bf16
    const float* __restrict__ xproj,   // [4096][3072] f32 rows t*16+m
    const float* __restrict__ bias1,   // recurrent bias [3072]
    float* __restrict__ hbuf,          // [2][16][1024] tagged f32 ping-pong
    short* __restrict__ gruout,        // [4096][1024] bf16 rows t*16+m
    const short* __restrict__ DwT,     // [32000][1024] bf16
    const float* __restrict__ db,      // [32000]
    float* __restrict__ out,           // [16*255][32000]
    unsigned* __restrict__ sync) {
  const int tid = threadIdx.x, lane = tid & 63, w = tid >> 6;
  const int r = lane & 15, q = lane >> 4;
  __shared__ s16x8 smem_v[2048];       // 32 KiB, shared between roles

  if (blockIdx.x < NBLK_SCAN) {
    // ================= scan role =================
    __builtin_amdgcn_s_setprio(3);
    typedef float RedT[4][3][64][4];   // 12 KiB each, double-buffered
    RedT* red = (RedT*)smem_v;
    const int c = blockIdx.x;
    s16x8 wb[3][8];
#pragma unroll
    for (int g = 0; g < 3; ++g)
#pragma unroll
      for (int s = 0; s < 8; ++s)
        wb[g][s] = *(const s16x8*)(WrecT + (size_t)(g * 1024 + c * 16 + r) * 1024 +
                                   (w * 8 + s) * 32 + q * 8);

    const int m = tid >> 4, nl = tid & 15, col = c * 16 + nl;
    const float bz = bias1[col], brr = bias1[1024 + col], bhh = bias1[2048 + col];
    const float* xb = xproj + (size_t)m * G_;   // row t*16+m => base + t*16*G_
    float* hb0 = hbuf;
    float* hb1 = hbuf + 16 * 1024;
    float h = hb0[m * 1024 + col];   // tagged latent; tag bits negligible
    float xz = xb[col], xr = xb[1024 + col], xh = xb[2048 + col];

    for (int t = 0; t < TSTEPS; ++t) {
      const float* hcur = (t & 1) ? hb1 : hb0;
      float* hnxt = (t & 1) ? hb0 : hb1;
      const unsigned tg = (unsigned)((t >> 1) & 3);
      // ---- cheap sample poll: 4 dwords/lane covering all 4 producer waves
      {
        const unsigned* su = (const unsigned*)hcur + lane * 16;  // col 16*lane
        for (;;) {
          unsigned s0, s1, s2, s3;
          asm volatile(
              "global_load_dword %0, %4, off sc0 sc1\n\t"
              "global_load_dword %1, %5, off sc0 sc1\n\t"
              "global_load_dword %2, %6, off sc0 sc1\n\t"
              "global_load_dword %3, %7, off sc0 sc1\n\t"
              "s_waitcnt vmcnt(0)"
              : "=&v"(s0), "=&v"(s1), "=&v"(s2), "=&v"(s3)
              : "v"(su), "v"(su + 4 * 1024), "v"(su + 8 * 1024),
                "v"(su + 12 * 1024)
              : "memory");
          const unsigned mism =
              ((s0 ^ tg) | (s1 ^ tg) | (s2 ^ tg) | (s3 ^ tg)) & 3u;
          if (__all(mism == 0u)) break;
          __builtin_amdgcn_s_sleep(1);
        }
      }
      // ---- full fragment load + per-dword verify (safety net, rarely loops)
      const float* lb = hcur + r * 1024 + w * 256 + q * 8;
      i32x4 va[16];
      for (;;) {
#pragma unroll
        for (int s = 0; s < 8; ++s) {
          GLD_SC(va[2 * s], lb + s * 32);
          GLD_SC(va[2 * s + 1], lb + s * 32 + 4);
        }
        asm volatile("s_waitcnt vmcnt(0)" ::: "memory");
        __builtin_amdgcn_sched_barrier(0);
        unsigned bad = 0;
#pragma unroll
        for (int k2 = 0; k2 < 16; ++k2) {
          bad |= (unsigned)(va[k2][0] ^ tg) | (unsigned)(va[k2][1] ^ tg) |
                 (unsigned)(va[k2][2] ^ tg) | (unsigned)(va[k2][3] ^ tg);
        }
        if (__all((bad & 3u) == 0u)) break;
        __builtin_amdgcn_s_sleep(1);
      }
      // f32 -> bf16 fragments in-register
      s16x8 af[8];
#pragma unroll
      for (int s = 0; s < 8; ++s) {
        union { unsigned u[4]; s16x8 v; } pk;
        pk.u[0] = cvtpk(__int_as_float(va[2*s][0]), __int_as_float(va[2*s][1]));
        pk.u[1] = cvtpk(__int_as_float(va[2*s][2]), __int_as_float(va[2*s][3]));
        pk.u[2] = cvtpk(__int_as_float(va[2*s+1][0]), __int_as_float(va[2*s+1][1]));
        pk.u[3] = cvtpk(__int_as_float(va[2*s+1][2]), __int_as_float(va[2*s+1][3]));
        af[s] = pk.v;
      }
      f32x4 acc[3] = {};
#pragma unroll
      for (int s = 0; s < 8; ++s) {
        acc[0] = __builtin_amdgcn_mfma_f32_16x16x32_bf16(af[s], wb[0][s], acc[0], 0, 0, 0);
        acc[1] = __builtin_amdgcn_mfma_f32_16x16x32_bf16(af[s], wb[1][s], acc[1], 0, 0, 0);
        acc[2] = __builtin_amdgcn_mfma_f32_16x16x32_bf16(af[s], wb[2][s], acc[2], 0, 0, 0);
      }
      *(f32x4*)&red[t & 1][w][0][lane][0] = acc[0];
      *(f32x4*)&red[t & 1][w][1][lane][0] = acc[1];
      *(f32x4*)&red[t & 1][w][2][lane][0] = acc[2];
      __syncthreads();   // the ONLY per-step barrier
      const int rl = (m >> 2) * 16 + nl, ri = m & 3;
      float rz = bz, rr2 = brr, rh = bhh;
#pragma unroll
      for (int ww = 0; ww < 4; ++ww) {
        rz += red[t & 1][ww][0][rl][ri];
        rr2 += red[t & 1][ww][1][rl][ri];
        rh += red[t & 1][ww][2][rl][ri];
      }
      const float z = frcp(1.f + __expf(-(xz + rz)));
      const float rg = frcp(1.f + __expf(-(xr + rr2)));
      const float hh = tanhf(xh + rg * rh);
      h = z * h + (1.f - z) * hh;   // h stays f32 locally
      // publish h(t+1): tagged f32 store IS the publication
      const unsigned ntg = (unsigned)(((t + 1) >> 1) & 3);
      const unsigned hu = (__float_as_uint(h) & ~3u) | ntg;
      __hip_atomic_store((unsigned*)hnxt + (m * 1024 + col), hu,
                         __ATOMIC_RELAXED, __HIP_MEMORY_SCOPE_AGENT);
      // gruout (bf16-packed), off critical path
      const unsigned hb16 = (unsigned short)f2bf(h);
      const unsigned nb = __shfl(hb16, lane | 1, 64);
      const unsigned pv = hb16 | (nb << 16);
      if (!(tid & 1))
        __hip_atomic_store((unsigned*)gruout + (((size_t)(t * 16 + m)) * 1024 + col) / 2,
                           pv, __ATOMIC_RELAXED, __HIP_MEMORY_SCOPE_AGENT);
      if ((t & 7) == 7) {  // worker-frontier flag, 1-in-8 steps
        asm volatile("s_waitcnt vmcnt(0)" ::: "memory");
        __syncthreads();
        if (tid == 0)
          __hip_atomic_store(&sync[c * FSTRIDE], (unsigned)(t + 1),
                             __ATOMIC_RELAXED, __HIP_MEMORY_SCOPE_AGENT);
      }
      {  // prefetch next step's x slice (pad rows exist: zero teacher)
        const float* xn = xb + (size_t)(t + 1) * 16 * G_;
        xz = xn[col]; xr = xn[1024 + col]; xh = xn[2048 + col];
      }
    }
    // epilogue: final gruout visibility, flag -> 256
    asm volatile("s_waitcnt vmcnt(0)" ::: "memory");
    __syncthreads();
    if (tid == 0)
      __hip_atomic_store(&sync[c * FSTRIDE], 256u,
                         __ATOMIC_RELAXED, __HIP_MEMORY_SCOPE_AGENT);
  } else {
    // ================= dense GEMM worker role =================
    // LDS: buf{0,1} x (A[128][32] | B[128][32]) bf16, XOR-swizzled 16B slots.
    char* sb = (char*)smem_v;
    const int wr = w >> 1, wc = w & 1;
    const int xterm = ((q ^ ((r >> 1) & 3)) << 4);              // LDS slot swz
    const int swz8 = (((lane & 3) ^ ((lane >> 3) & 3)) << 3);   // src col swz
    const int j = blockIdx.x - NBLK_SCAN;  // 0..447
#pragma unroll 1
    for (int tq = j; tq < NTILE_RB * NTILE_CB; tq += NWORK) {
      const int rb = tq / NTILE_CB, cb = tq - rb * NTILE_CB;
      const unsigned need = (unsigned)(rb < 31 ? 8 * rb + 8 : 256);
      unsigned v = __hip_atomic_load(&sync[lane * FSTRIDE], __ATOMIC_RELAXED,
                                     __HIP_MEMORY_SCOPE_AGENT);
      while (!__all(v >= need)) {
        __builtin_amdgcn_s_sleep(32);
        v = __hip_atomic_load(&sync[lane * FSTRIDE], __ATOMIC_RELAXED,
                              __HIP_MEMORY_SCOPE_AGENT);
      }
      const short* Ag = gruout + (size_t)rb * 128 * 1024;  // cached: coherent
      const short* Bg = DwT + (size_t)cb * 128 * 1024;
      f32x4 acc[4][4] = {};
#define STAGE(buf, kk)                                                         \
  {                                                                            \
    _Pragma("unroll") for (int it = 0; it < 2; ++it) {                         \
      const size_t go = (size_t)(w * 32 + it * 16 + (lane >> 2)) * 1024 +      \
                        (kk) * 32 + swz8;                                      \
      char* lb2 = sb + (buf) * 16384 + w * 2048 + it * 1024;                   \
      gload_lds16(Ag + go, lb2);                                               \
      gload_lds16(Bg + go, lb2 + 8192);                                        \
    }                                                                          \
  }
      STAGE(0, 0)
#pragma unroll 1
      for (int kk = 0; kk < 32; ++kk) {
        __syncthreads();             // staged kk visible; prev buf reads done
        if (kk < 31) STAGE((kk + 1) & 1, kk + 1)
        const char* ab = sb + (kk & 1) * 16384;
        s16x8 af[4], bf[4];
#pragma unroll
        for (int i = 0; i < 4; ++i)
          af[i] = *(const s16x8*)(ab + (wr * 64 + i * 16 + r) * 64 + xterm);
#pragma unroll
        for (int j5 = 0; j5 < 4; ++j5)
          bf[j5] = *(const s16x8*)(ab + 8192 + (wc * 64 + j5 * 16 + r) * 64 + xterm);
#pragma unroll
        for (int i = 0; i < 4; ++i)
#pragma unroll
          for (int j5 = 0; j5 < 4; ++j5)
            acc[i][j5] = __builtin_amdgcn_mfma_f32_16x16x32_bf16(
                af[i], bf[j5], acc[i][j5], 0, 0, 0);
      }
#undef STAGE
      const int wm = rb * 128 + wr * 64, wn = cb * 128 + wc * 64;
#pragma unroll
      for (int j2 = 0; j2 < 4; ++j2) {
        const int col = wn + j2 * 16 + r;
        const float bv = db[col];
#pragma unroll
        for (int i = 0; i < 4; ++i) {
#pragma unroll
          for (int rr = 0; rr < 4; ++rr) {
            const int arow = wm + i * 16 + q * 4 + rr;
            const int t = arow >> 4, mm = arow & 15;
            if (t < TSTEPS)
              __builtin_nontemporal_store(
                  acc[i][j2][rr] + bv,
                  &out[(size_t)(mm * TSTEPS + t) * V_ + col]);
          }
        }
      }
      __syncthreads();  // LDS WAR: next tile's STAGE(0,0) vs this tile's reads
    }
  }
}

// ---------- launch ----------
extern "C" void kernel_launch(void* const* d_in, const int* in_sizes, int n_in,
                              void* d_out, int out_size, void* d_ws, size_t ws_size,
                              hipStream_t stream) {
  const float* latent = (const float*)d_in[0];
  const float* trueo  = (const float*)d_in[1];
  const float* gk     = (const float*)d_in[2];
  const float* grk    = (const float*)d_in[3];
  const float* gbias  = (const float*)d_in[4];
  const float* dw     = (const float*)d_in[5];
  const float* db     = (const float*)d_in[6];
  float* out = (float*)d_out;
  char* ws = (char*)d_ws;
  short*    WrecT  = (short*)(ws + 0);          //  6,291,456  [3072][1024] bf16
  short*    GkT    = (short*)(ws + 6291456);    //  3,145,728  [3072][512]  bf16
  short*    DwT    = (short*)(ws + 9437184);    // 65,536,000  [32000][1024] bf16
  short*    teachA = (short*)(ws + 74973184);   //  4,194,304  [4096][512]  bf16 rows t*16+b
  float*    hbuf   = (float*)(ws + 74973184);   //    131,072  [2][16][1024] tagged f32
                                                //  (aliases teachA: init_h runs AFTER
                                                //   the xproj GEMM consumed teachA;
                                                //   pack_teacher rewrites it each call)
  float*    xproj  = (float*)(ws + 79167488);   // 50,331,648  [4096][3072] f32 rows t*16+m
  short*    gruout = (short*)(ws + 129499136);  //  8,388,608  [4096][1024] bf16 rows t*16+m
  unsigned* syncb  = (unsigned*)(ws + 137953280); //    8,192  frontier flags[64*16]

  hipMemsetAsync(syncb, 0, 8192, stream);
  transpose_cvt<<<dim3(96, 32), dim3(32, 8), 0, stream>>>(grk, WrecT, 1024, 3072);
  transpose_cvt<<<dim3(96, 16), dim3(32, 8), 0, stream>>>(gk, GkT, 512, 3072);
  transpose_cvt<<<dim3(1000, 32), dim3(32, 8), 0, stream>>>(dw, DwT, 1024, 32000);
  pack_teacher<<<1024, 256, 0, stream>>>(trueo, teachA);
  gemm_bf16<<<dim3(24, 32), 256, 0, stream>>>(teachA, GkT, gbias, xproj, G_, E_);
  init_h<<<64, 256, 0, stream>>>(latent, hbuf);   // after xproj GEMM (aliasing)
  fused_scan_gemm<<<NBLK_TOT, 256, 0, stream>>>(WrecT, xproj, gbias + G_, hbuf,
                                                gruout, DwT, db, out, syncb);
}

// Round 9
// 980.259 us; speedup vs baseline: 1.2719x; 1.2687x over previous
//
#include <hip/hip_runtime.h>

// RecurrentDecoder: x_proj GEMM -> ONE fused persistent kernel:
//   blocks 0..63   = GRU scan, R5 flag protocol + 8-WAY REPLICATION of the
//                    h ping-pong and scan flags (consumer WG c reads replica
//                    c&7) to cut L3 line-service fan-out 64 -> 8.
//   blocks 64..511 = dense-GEMM workers (R8 verbatim: LDS dbuf global_load_lds
//                    pipeline, XOR-swizzled, nt stores), gated by frontier
//                    flags published every 8 steps.

typedef __attribute__((ext_vector_type(8))) short s16x8;  // 8 bf16 (4 VGPRs)
typedef __attribute__((ext_vector_type(4))) float f32x4;
typedef __attribute__((ext_vector_type(4))) int   i32x4;

#define B_      16
#define TSTEPS  255
#define H_      1024
#define G_      3072
#define E_      512
#define V_      32000
#define MROWS   4080   // B_*TSTEPS
#define MPAD    4096
#define NBLK_SCAN 64
#define NWORK     448
#define NBLK_TOT  512
#define NTILE_RB  32    // 4096/128
#define NTILE_CB  250   // 32000/128
#define FSTRIDE   16    // flags padded to 64B
#define NCOPY     8     // h / scan-flag replicas
#define HCPY      16384 // shorts per h replica (16x1024 bf16)

__device__ __forceinline__ short f2bf(float f) {   // RNE f32 -> bf16 bits
  unsigned u = __float_as_uint(f);
  u = (u + 0x7fffu + ((u >> 16) & 1u)) >> 16;
  return (short)u;
}

__device__ __forceinline__ float frcp(float x) {
  float r;
  asm("v_rcp_f32 %0, %1" : "=v"(r) : "v"(x));
  return r;
}

// 16B load bypassing L1/L2 (sc0 sc1): reads meet write-through stores at L3
#define GLD_SC(dst, p)                                                         \
  asm volatile("global_load_dwordx4 %0, %1, off sc0 sc1"                       \
               : "=v"(dst) : "v"(p) : "memory")

// async global->LDS 16B: HW writes lane l at (wave-uniform) ldsbase + l*16
__device__ __forceinline__ void gload_lds16(const short* g, void* l) {
  __builtin_amdgcn_global_load_lds((const __attribute__((address_space(1))) void*)g,
                                   (__attribute__((address_space(3))) void*)l,
                                   16, 0, 0);
}

// ---------- prep kernels ----------

// src f32 [K][N] -> dst bf16 [N][K]
__global__ void transpose_cvt(const float* __restrict__ src, short* __restrict__ dst,
                              int K, int N) {
  __shared__ float tile[32][33];
  const int n0 = blockIdx.x * 32, k0 = blockIdx.y * 32;
  const int tx = threadIdx.x, ty0 = threadIdx.y;  // (32,8)
#pragma unroll
  for (int yy = 0; yy < 4; ++yy) {
    int ty = ty0 + yy * 8;
    tile[ty][tx] = src[(size_t)(k0 + ty) * N + (n0 + tx)];
  }
  __syncthreads();
#pragma unroll
  for (int yy = 0; yy < 4; ++yy) {
    int ty = ty0 + yy * 8;
    dst[(size_t)(n0 + ty) * K + (k0 + tx)] = f2bf(tile[tx][ty]);
  }
}

// true_outputs (16,256,512) f32 -> teacher A bf16 [4096][512], row = t*16+b
__global__ void pack_teacher(const float* __restrict__ src, short* __restrict__ dst) {
  int idx = blockIdx.x * 256 + threadIdx.x;  // 262144 total
  int row = idx >> 6;
  int c8 = (idx & 63) << 3;
  int t = row >> 4, b = row & 15;
  s16x8 v = {};
  if (t < TSTEPS) {
    const float* s = src + ((size_t)(b * 256 + t)) * E_ + c8;
#pragma unroll
    for (int j = 0; j < 8; ++j) v[j] = f2bf(s[j]);
  }
  *(s16x8*)(dst + (size_t)row * E_ + c8) = v;
}

// buf0: 8 replicas of bf16(latent)
__global__ void init_h(const float* __restrict__ latent, short* __restrict__ hb) {
  int i = blockIdx.x * 256 + threadIdx.x;  // 16384
  const short v = f2bf(latent[i]);
#pragma unroll
  for (int cp = 0; cp < NCOPY; ++cp) hb[cp * HCPY + i] = v;
}

// ---------- plain GEMM (xproj only; dispatch-boundary coherence) ----------
__global__ __launch_bounds__(256) void gemm_bf16(
    const short* __restrict__ A, const short* __restrict__ BT,
    const float* __restrict__ bias, float* __restrict__ C, int N, int K) {
  const int tid = threadIdx.x;
  const int lane = tid & 63, w = tid >> 6;
  const int r = lane & 15, q = lane >> 4;
  const int bm = blockIdx.y * 128, bn = blockIdx.x * 128;
  const int wm = bm + (w >> 1) * 64, wn = bn + (w & 1) * 64;
  const short* Ab = A + (size_t)(wm + r) * K + q * 8;
  const short* Bb = BT + (size_t)(wn + r) * K + q * 8;
  f32x4 acc[4][4] = {};
  s16x8 a0[4], b0[4], a1[4], b1[4];
  const int nk = K >> 5;
#define GL(AA, BB, kk)                                                         \
  {                                                                            \
    _Pragma("unroll") for (int i = 0; i < 4; ++i) {                            \
      AA[i] = *(const s16x8*)(Ab + (size_t)i * 16 * K + (kk) * 32);            \
    }                                                                          \
    _Pragma("unroll") for (int j = 0; j < 4; ++j) {                            \
      BB[j] = *(const s16x8*)(Bb + (size_t)j * 16 * K + (kk) * 32);            \
    }                                                                          \
  }
#define MM(AA, BB)                                                             \
  {                                                                            \
    _Pragma("unroll") for (int i = 0; i < 4; ++i)                              \
        _Pragma("unroll") for (int j = 0; j < 4; ++j)                          \
            acc[i][j] = __builtin_amdgcn_mfma_f32_16x16x32_bf16(               \
                AA[i], BB[j], acc[i][j], 0, 0, 0);                             \
  }
  GL(a0, b0, 0)
#pragma unroll 1
  for (int ks = 0; ks < nk; ks += 2) {
    GL(a1, b1, ks + 1)
    MM(a0, b0)
    if (ks + 2 < nk) GL(a0, b0, ks + 2)
    MM(a1, b1)
  }
#undef GL
#undef MM
#pragma unroll
  for (int j = 0; j < 4; ++j) {
    const int col = wn + j * 16 + r;
    const float bv = bias[col];
#pragma unroll
    for (int i = 0; i < 4; ++i) {
#pragma unroll
      for (int rr = 0; rr < 4; ++rr) {
        const int row = wm + i * 16 + q * 4 + rr;
        C[(size_t)row * N + col] = acc[i][j][rr] + bv;
      }
    }
  }
}

// ---------- fused persistent scan + dense GEMM ----------
// sync: [0 .. 8*1024)      scan flags, 8 replicas x 64 WGs x 64B
//       [8192 .. 8192+1024) frontier flags (workers), 64 x 64B
__global__ __launch_bounds__(256, 2) void fused_scan_gemm(
    const short* __restrict__ WrecT,   // [3072][1024] bf16
    const float* __restrict__ xproj,   // [4096][3072] f32 rows t*16+m
    const float* __restrict__ bias1,   // recurrent bias [3072]
    const float* __restrict__ latent,  // [16][1024] f32
    short* __restrict__ hbuf,          // [2][8][16][1024] bf16 replicated pp
    short* __restrict__ gruout,        // [4096][1024] bf16 rows t*16+m
    const short* __restrict__ DwT,     // [32000][1024] bf16
    const float* __restrict__ db,      // [32000]
    float* __restrict__ out,           // [16*255][32000]
    unsigned* __restrict__ sync) {
  const int tid = threadIdx.x, lane = tid & 63, w = tid >> 6;
  const int r = lane & 15, q = lane >> 4;
  __shared__ s16x8 smem_v[2048];       // 32 KiB, shared between roles
  unsigned* scanflag = sync;
  unsigned* frontier = sync + NCOPY * 1024;

  if (blockIdx.x < NBLK_SCAN) {
    // ================= scan role (R5 protocol + 8-way replication) ========
    __builtin_amdgcn_s_setprio(3);
    float (*red)[3][64][4] = (float(*)[3][64][4])smem_v;   // 12 KiB
    const int c = blockIdx.x;
    const int cp = c & 7;              // my read replica
    s16x8 wb[3][8];
#pragma unroll
    for (int g = 0; g < 3; ++g)
#pragma unroll
      for (int s = 0; s < 8; ++s)
        wb[g][s] = *(const s16x8*)(WrecT + (size_t)(g * 1024 + c * 16 + r) * 1024 +
                                   (w * 8 + s) * 32 + q * 8);

    const int m = tid >> 4, nl = tid & 15, col = c * 16 + nl;
    float h = latent[m * 1024 + col];
    const float bz = bias1[col], brr = bias1[1024 + col], bhh = bias1[2048 + col];
    const float* xb = xproj + (size_t)m * G_;   // row t*16+m => base + t*16*G_
    float xz = xb[col], xr = xb[1024 + col], xh = xb[2048 + col];

    for (int t = 0; t < TSTEPS; ++t) {
      const short* hcur = hbuf + ((size_t)((t & 1) * NCOPY + cp)) * HCPY;
      unsigned* hnxt = (unsigned*)(hbuf + (size_t)((t & 1) ^ 1) * NCOPY * HCPY);
      i32x4 afi[8];
#pragma unroll
      for (int s = 0; s < 8; ++s)
        GLD_SC(afi[s], hcur + r * 1024 + (w * 8 + s) * 32 + q * 8);
      asm volatile("s_waitcnt vmcnt(0)"
                   : "+v"(afi[0]), "+v"(afi[1]), "+v"(afi[2]), "+v"(afi[3]),
                     "+v"(afi[4]), "+v"(afi[5]), "+v"(afi[6]), "+v"(afi[7])
                   :: "memory");
      __builtin_amdgcn_sched_barrier(0);
      f32x4 acc[3] = {};
#pragma unroll
      for (int s = 0; s < 8; ++s) {
        const s16x8 af = *(const s16x8*)&afi[s];
        acc[0] = __builtin_amdgcn_mfma_f32_16x16x32_bf16(af, wb[0][s], acc[0], 0, 0, 0);
        acc[1] = __builtin_amdgcn_mfma_f32_16x16x32_bf16(af, wb[1][s], acc[1], 0, 0, 0);
        acc[2] = __builtin_amdgcn_mfma_f32_16x16x32_bf16(af, wb[2][s], acc[2], 0, 0, 0);
      }
      *(f32x4*)&red[w][0][lane][0] = acc[0];
      *(f32x4*)&red[w][1][lane][0] = acc[1];
      *(f32x4*)&red[w][2][lane][0] = acc[2];
      __syncthreads();  // also drains prev-step gruout + xproj prefetch
      const int rl = (m >> 2) * 16 + nl, ri = m & 3;
      float rz = bz, rr2 = brr, rh = bhh;
#pragma unroll
      for (int ww = 0; ww < 4; ++ww) {
        rz += red[ww][0][rl][ri];
        rr2 += red[ww][1][rl][ri];
        rh += red[ww][2][rl][ri];
      }
      const float z = frcp(1.f + __expf(-(xz + rz)));
      const float rg = frcp(1.f + __expf(-(xr + rr2)));
      const float hh = tanhf(xh + rg * rh);
      h = z * h + (1.f - z) * hh;   // h stays f32 locally
      const unsigned hb16 = (unsigned short)f2bf(h);
      const unsigned nb = __shfl(hb16, lane | 1, 64);
      const unsigned pv = hb16 | (nb << 16);
      const unsigned hoff = (unsigned)((m * 1024 + col) >> 1);
      if (!(tid & 1)) {
#pragma unroll
        for (int cp2 = 0; cp2 < NCOPY; ++cp2)
          __hip_atomic_store(hnxt + cp2 * (HCPY / 2) + hoff, pv,
                             __ATOMIC_RELAXED, __HIP_MEMORY_SCOPE_AGENT);
      }
      __syncthreads();  // drains the h replica stores -> L3
      if (tid == 0) {
#pragma unroll
        for (int cp2 = 0; cp2 < NCOPY; ++cp2)
          __hip_atomic_store(&scanflag[cp2 * 1024 + c * FSTRIDE], (unsigned)(t + 1),
                             __ATOMIC_RELAXED, __HIP_MEMORY_SCOPE_AGENT);
      }
      // ---- off-critical-path traffic ----
      if (!(tid & 1))
        __hip_atomic_store((unsigned*)gruout + (((size_t)(t * 16 + m)) * 1024 + col) / 2,
                           pv, __ATOMIC_RELAXED, __HIP_MEMORY_SCOPE_AGENT);
      if ((t & 7) == 7) {  // worker-frontier flag, 1-in-8 steps
        asm volatile("s_waitcnt vmcnt(0)" ::: "memory");
        __syncthreads();
        if (tid == 0)
          __hip_atomic_store(&frontier[c * FSTRIDE], (unsigned)(t + 1),
                             __ATOMIC_RELAXED, __HIP_MEMORY_SCOPE_AGENT);
      }
      {  // prefetch next step's x slice (pad rows exist: zero teacher)
        const float* xn = xb + (size_t)(t + 1) * 16 * G_;
        xz = xn[col]; xr = xn[1024 + col]; xh = xn[2048 + col];
      }
      if (t < TSTEPS - 1) {  // poll my replica's 64 flags (no sleep: self-paced)
        const unsigned* fp = &scanflag[cp * 1024 + lane * FSTRIDE];
        unsigned v = __hip_atomic_load(fp, __ATOMIC_RELAXED,
                                       __HIP_MEMORY_SCOPE_AGENT);
        while (!__all(v > (unsigned)t))
          v = __hip_atomic_load(fp, __ATOMIC_RELAXED, __HIP_MEMORY_SCOPE_AGENT);
      }
    }
    // epilogue: final gruout visibility, frontier -> 256
    asm volatile("s_waitcnt vmcnt(0)" ::: "memory");
    __syncthreads();
    if (tid == 0)
      __hip_atomic_store(&frontier[c * FSTRIDE], 256u,
                         __ATOMIC_RELAXED, __HIP_MEMORY_SCOPE_AGENT);
  } else {
    // ================= dense GEMM worker role (R8 verbatim) ===============
    char* sb = (char*)smem_v;
    const int wr = w >> 1, wc = w & 1;
    const int xterm = ((q ^ ((r >> 1) & 3)) << 4);              // LDS slot swz
    const int swz8 = (((lane & 3) ^ ((lane >> 3) & 3)) << 3);   // src col swz
    const int j = blockIdx.x - NBLK_SCAN;  // 0..447
#pragma unroll 1
    for (int tq = j; tq < NTILE_RB * NTILE_CB; tq += NWORK) {
      const int rb = tq / NTILE_CB, cb = tq - rb * NTILE_CB;
      const unsigned need = (unsigned)(rb < 31 ? 8 * rb + 8 : 256);
      unsigned v = __hip_atomic_load(&frontier[lane * FSTRIDE], __ATOMIC_RELAXED,
                                     __HIP_MEMORY_SCOPE_AGENT);
      while (!__all(v >= need)) {
        __builtin_amdgcn_s_sleep(32);
        v = __hip_atomic_load(&frontier[lane * FSTRIDE], __ATOMIC_RELAXED,
                              __HIP_MEMORY_SCOPE_AGENT);
      }
      const short* Ag = gruout + (size_t)rb * 128 * 1024;  // cached: coherent
      const short* Bg = DwT + (size_t)cb * 128 * 1024;
      f32x4 acc[4][4] = {};
#define STAGE(buf, kk)                                                         \
  {                                                                            \
    _Pragma("unroll") for (int it = 0; it < 2; ++it) {                         \
      const size_t go = (size_t)(w * 32 + it * 16 + (lane >> 2)) * 1024 +      \
                        (kk) * 32 + swz8;                                      \
      char* lb2 = sb + (buf) * 16384 + w * 2048 + it * 1024;                   \
      gload_lds16(Ag + go, lb2);                                               \
      gload_lds16(Bg + go, lb2 + 8192);                                        \
    }                                                                          \
  }
      STAGE(0, 0)
#pragma unroll 1
      for (int kk = 0; kk < 32; ++kk) {
        __syncthreads();             // staged kk visible; prev buf reads done
        if (kk < 31) STAGE((kk + 1) & 1, kk + 1)
        const char* ab = sb + (kk & 1) * 16384;
        s16x8 af[4], bf[4];
#pragma unroll
        for (int i = 0; i < 4; ++i)
          af[i] = *(const s16x8*)(ab + (wr * 64 + i * 16 + r) * 64 + xterm);
#pragma unroll
        for (int j5 = 0; j5 < 4; ++j5)
          bf[j5] = *(const s16x8*)(ab + 8192 + (wc * 64 + j5 * 16 + r) * 64 + xterm);
#pragma unroll
        for (int i = 0; i < 4; ++i)
#pragma unroll
          for (int j5 = 0; j5 < 4; ++j5)
            acc[i][j5] = __builtin_amdgcn_mfma_f32_16x16x32_bf16(
                af[i], bf[j5], acc[i][j5], 0, 0, 0);
      }
#undef STAGE
      const int wm = rb * 128 + wr * 64, wn = cb * 128 + wc * 64;
#pragma unroll
      for (int j2 = 0; j2 < 4; ++j2) {
        const int col = wn + j2 * 16 + r;
        const float bv = db[col];
#pragma unroll
        for (int i = 0; i < 4; ++i) {
#pragma unroll
          for (int rr = 0; rr < 4; ++rr) {
            const int arow = wm + i * 16 + q * 4 + rr;
            const int t = arow >> 4, mm = arow & 15;
            if (t < TSTEPS)
              __builtin_nontemporal_store(
                  acc[i][j2][rr] + bv,
                  &out[(size_t)(mm * TSTEPS + t) * V_ + col]);
          }
        }
      }
      __syncthreads();  // LDS WAR: next tile's STAGE(0,0) vs this tile's reads
    }
  }
}

// ---------- launch ----------
extern "C" void kernel_launch(void* const* d_in, const int* in_sizes, int n_in,
                              void* d_out, int out_size, void* d_ws, size_t ws_size,
                              hipStream_t stream) {
  const float* latent = (const float*)d_in[0];
  const float* trueo  = (const float*)d_in[1];
  const float* gk     = (const float*)d_in[2];
  const float* grk    = (const float*)d_in[3];
  const float* gbias  = (const float*)d_in[4];
  const float* dw     = (const float*)d_in[5];
  const float* db     = (const float*)d_in[6];
  float* out = (float*)d_out;
  char* ws = (char*)d_ws;
  short*    WrecT  = (short*)(ws + 0);          //  6,291,456  [3072][1024] bf16
  short*    GkT    = (short*)(ws + 6291456);    //  3,145,728  [3072][512]  bf16
  short*    DwT    = (short*)(ws + 9437184);    // 65,536,000  [32000][1024] bf16
  short*    teachA = (short*)(ws + 74973184);   //  4,194,304  [4096][512]  bf16 rows t*16+b
  // The following alias teachA's storage; they are (re)initialized AFTER the
  // xproj GEMM consumed teachA, and pack_teacher rewrites teachA every call.
  short*    hbuf   = (short*)(ws + 74973184);   //    524,288  [2][8][16][1024] bf16
  unsigned* syncb  = (unsigned*)(ws + 75497472);//     36,864  scanflags(8x64) + frontier
  float*    xproj  = (float*)(ws + 79167488);   // 50,331,648  [4096][3072] f32 rows t*16+m
  short*    gruout = (short*)(ws + 129499136);  //  8,388,608  [4096][1024] bf16 rows t*16+m

  transpose_cvt<<<dim3(96, 32), dim3(32, 8), 0, stream>>>(grk, WrecT, 1024, 3072);
  transpose_cvt<<<dim3(96, 16), dim3(32, 8), 0, stream>>>(gk, GkT, 512, 3072);
  transpose_cvt<<<dim3(1000, 32), dim3(32, 8), 0, stream>>>(dw, DwT, 1024, 32000);
  pack_teacher<<<1024, 256, 0, stream>>>(trueo, teachA);
  gemm_bf16<<<dim3(24, 32), 256, 0, stream>>>(teachA, GkT, gbias, xproj, G_, E_);
  hipMemsetAsync(syncb, 0, 36864, stream);        // after pack_teacher (aliasing)
  init_h<<<64, 256, 0, stream>>>(latent, hbuf);   // after xproj GEMM (aliasing)
  fused_scan_gemm<<<NBLK_TOT, 256, 0, stream>>>(WrecT, xproj, gbias + G_, latent,
                                                hbuf, gruout, DwT, db, out, syncb);
}

// Round 10
// 917.732 us; speedup vs baseline: 1.3585x; 1.0681x over previous
//
#include <hip/hip_runtime.h>

// RecurrentDecoder: x_proj GEMM -> ONE fused persistent kernel:
//   blocks 0..63   = GRU scan. h exchanged through an APPEND-ONLY history
//                    buffer (hist row-block t = h(t)): producers write-through
//                    once; consumers use NORMAL CACHED loads (first touch
//                    after write => coherent; per-XCD L2 serves 8 WGs from one
//                    L3 fetch). R5 flag protocol (sc-bypass, 64B-padded).
//   blocks 64..511 = dense-GEMM workers (LDS dbuf global_load_lds pipeline,
//                    XOR-swizzled, nt stores), reading A from hist+16 rows,
//                    gated by frontier flags published every 8 steps.

typedef __attribute__((ext_vector_type(8))) short s16x8;  // 8 bf16 (4 VGPRs)
typedef __attribute__((ext_vector_type(4))) float f32x4;
typedef __attribute__((ext_vector_type(4))) int   i32x4;

#define B_      16
#define TSTEPS  255
#define H_      1024
#define G_      3072
#define E_      512
#define V_      32000
#define MROWS   4080   // B_*TSTEPS
#define MPAD    4096
#define NBLK_SCAN 64
#define NWORK     448
#define NBLK_TOT  512
#define NTILE_RB  32    // 4096/128
#define NTILE_CB  250   // 32000/128
#define FSTRIDE   16    // flags padded to 64B

__device__ __forceinline__ short f2bf(float f) {   // RNE f32 -> bf16 bits
  unsigned u = __float_as_uint(f);
  u = (u + 0x7fffu + ((u >> 16) & 1u)) >> 16;
  return (short)u;
}

__device__ __forceinline__ float frcp(float x) {
  float r;
  asm("v_rcp_f32 %0, %1" : "=v"(r) : "v"(x));
  return r;
}

// normal cached 16B load (L1/L2 path) — for append-only hist reads
#define GLD_C(dst, p)                                                          \
  asm volatile("global_load_dwordx4 %0, %1, off"                               \
               : "=v"(dst) : "v"(p) : "memory")

// async global->LDS 16B: HW writes lane l at (wave-uniform) ldsbase + l*16
__device__ __forceinline__ void gload_lds16(const short* g, void* l) {
  __builtin_amdgcn_global_load_lds((const __attribute__((address_space(1))) void*)g,
                                   (__attribute__((address_space(3))) void*)l,
                                   16, 0, 0);
}

// ---------- prep kernels ----------

// src f32 [K][N] -> dst bf16 [N][K]
__global__ void transpose_cvt(const float* __restrict__ src, short* __restrict__ dst,
                              int K, int N) {
  __shared__ float tile[32][33];
  const int n0 = blockIdx.x * 32, k0 = blockIdx.y * 32;
  const int tx = threadIdx.x, ty0 = threadIdx.y;  // (32,8)
#pragma unroll
  for (int yy = 0; yy < 4; ++yy) {
    int ty = ty0 + yy * 8;
    tile[ty][tx] = src[(size_t)(k0 + ty) * N + (n0 + tx)];
  }
  __syncthreads();
#pragma unroll
  for (int yy = 0; yy < 4; ++yy) {
    int ty = ty0 + yy * 8;
    dst[(size_t)(n0 + ty) * K + (k0 + tx)] = f2bf(tile[tx][ty]);
  }
}

// true_outputs (16,256,512) f32 -> teacher A bf16 [4096][512], row = t*16+b
__global__ void pack_teacher(const float* __restrict__ src, short* __restrict__ dst) {
  int idx = blockIdx.x * 256 + threadIdx.x;  // 262144 total
  int row = idx >> 6;
  int c8 = (idx & 63) << 3;
  int t = row >> 4, b = row & 15;
  s16x8 v = {};
  if (t < TSTEPS) {
    const float* s = src + ((size_t)(b * 256 + t)) * E_ + c8;
#pragma unroll
    for (int j = 0; j < 8; ++j) v[j] = f2bf(s[j]);
  }
  *(s16x8*)(dst + (size_t)row * E_ + c8) = v;
}

// hist rows 0..15 = bf16(latent) = h(0)
__global__ void init_h(const float* __restrict__ latent, short* __restrict__ hist) {
  int i = blockIdx.x * 256 + threadIdx.x;  // 16384
  hist[i] = f2bf(latent[i]);
}

// ---------- plain GEMM (xproj only; dispatch-boundary coherence) ----------
__global__ __launch_bounds__(256) void gemm_bf16(
    const short* __restrict__ A, const short* __restrict__ BT,
    const float* __restrict__ bias, float* __restrict__ C, int N, int K) {
  const int tid = threadIdx.x;
  const int lane = tid & 63, w = tid >> 6;
  const int r = lane & 15, q = lane >> 4;
  const int bm = blockIdx.y * 128, bn = blockIdx.x * 128;
  const int wm = bm + (w >> 1) * 64, wn = bn + (w & 1) * 64;
  const short* Ab = A + (size_t)(wm + r) * K + q * 8;
  const short* Bb = BT + (size_t)(wn + r) * K + q * 8;
  f32x4 acc[4][4] = {};
  s16x8 a0[4], b0[4], a1[4], b1[4];
  const int nk = K >> 5;
#define GL(AA, BB, kk)                                                         \
  {                                                                            \
    _Pragma("unroll") for (int i = 0; i < 4; ++i) {                            \
      AA[i] = *(const s16x8*)(Ab + (size_t)i * 16 * K + (kk) * 32);            \
    }                                                                          \
    _Pragma("unroll") for (int j = 0; j < 4; ++j) {                            \
      BB[j] = *(const s16x8*)(Bb + (size_t)j * 16 * K + (kk) * 32);            \
    }                                                                          \
  }
#define MM(AA, BB)                                                             \
  {                                                                            \
    _Pragma("unroll") for (int i = 0; i < 4; ++i)                              \
        _Pragma("unroll") for (int j = 0; j < 4; ++j)                          \
            acc[i][j] = __builtin_amdgcn_mfma_f32_16x16x32_bf16(               \
                AA[i], BB[j], acc[i][j], 0, 0, 0);                             \
  }
  GL(a0, b0, 0)
#pragma unroll 1
  for (int ks = 0; ks < nk; ks += 2) {
    GL(a1, b1, ks + 1)
    MM(a0, b0)
    if (ks + 2 < nk) GL(a0, b0, ks + 2)
    MM(a1, b1)
  }
#undef GL
#undef MM
#pragma unroll
  for (int j = 0; j < 4; ++j) {
    const int col = wn + j * 16 + r;
    const float bv = bias[col];
#pragma unroll
    for (int i = 0; i < 4; ++i) {
#pragma unroll
      for (int rr = 0; rr < 4; ++rr) {
        const int row = wm + i * 16 + q * 4 + rr;
        C[(size_t)row * N + col] = acc[i][j][rr] + bv;
      }
    }
  }
}

// ---------- fused persistent scan + dense GEMM ----------
// sync: [0..1023] scan flags (sc-bypass, 64B apart); [1024..2047] frontier.
__global__ __launch_bounds__(256, 2) void fused_scan_gemm(
    const short* __restrict__ WrecT,   // [3072][1024] bf16
    const float* __restrict__ xproj,   // [4096][3072] f32 rows t*16+m
    const float* __restrict__ bias1,   // recurrent bias [3072]
    const float* __restrict__ latent,  // [16][1024] f32
    short* __restrict__ hist,          // [4112][1024] bf16; rows 16t.. = h(t)
    const short* __restrict__ DwT,     // [32000][1024] bf16
    const float* __restrict__ db,      // [32000]
    float* __restrict__ out,           // [16*255][32000]
    unsigned* __restrict__ sync) {
  const int tid = threadIdx.x, lane = tid & 63, w = tid >> 6;
  const int r = lane & 15, q = lane >> 4;
  __shared__ s16x8 smem_v[2048];       // 32 KiB, shared between roles
  unsigned* scanflag = sync;
  unsigned* frontier = sync + 1024;

  if (blockIdx.x < NBLK_SCAN) {
    // ================= scan role =================
    __builtin_amdgcn_s_setprio(3);
    float (*red)[3][64][4] = (float(*)[3][64][4])smem_v;   // 12 KiB
    const int c = blockIdx.x;
    s16x8 wb[3][8];
#pragma unroll
    for (int g = 0; g < 3; ++g)
#pragma unroll
      for (int s = 0; s < 8; ++s)
        wb[g][s] = *(const s16x8*)(WrecT + (size_t)(g * 1024 + c * 16 + r) * 1024 +
                                   (w * 8 + s) * 32 + q * 8);

    const int m = tid >> 4, nl = tid & 15, col = c * 16 + nl;
    float h = latent[m * 1024 + col];
    const float bz = bias1[col], brr = bias1[1024 + col], bhh = bias1[2048 + col];
    const float* xb = xproj + (size_t)m * G_;   // row t*16+m => base + t*16*G_
    float xz = xb[col], xr = xb[1024 + col], xh = xb[2048 + col];

    for (int t = 0; t < TSTEPS; ++t) {
      // h(t) fragment: NORMAL cached loads from append-only hist rows 16t..
      const short* hrow = hist + ((size_t)t * 16 + r) * 1024 + w * 256 + q * 8;
      i32x4 afi[8];
#pragma unroll
      for (int s = 0; s < 8; ++s) GLD_C(afi[s], hrow + s * 32);
      asm volatile("s_waitcnt vmcnt(0)"
                   : "+v"(afi[0]), "+v"(afi[1]), "+v"(afi[2]), "+v"(afi[3]),
                     "+v"(afi[4]), "+v"(afi[5]), "+v"(afi[6]), "+v"(afi[7])
                   :: "memory");
      __builtin_amdgcn_sched_barrier(0);
      f32x4 acc[3] = {};
#pragma unroll
      for (int s = 0; s < 8; ++s) {
        const s16x8 af = *(const s16x8*)&afi[s];
        acc[0] = __builtin_amdgcn_mfma_f32_16x16x32_bf16(af, wb[0][s], acc[0], 0, 0, 0);
        acc[1] = __builtin_amdgcn_mfma_f32_16x16x32_bf16(af, wb[1][s], acc[1], 0, 0, 0);
        acc[2] = __builtin_amdgcn_mfma_f32_16x16x32_bf16(af, wb[2][s], acc[2], 0, 0, 0);
      }
      *(f32x4*)&red[w][0][lane][0] = acc[0];
      *(f32x4*)&red[w][1][lane][0] = acc[1];
      *(f32x4*)&red[w][2][lane][0] = acc[2];
      __syncthreads();  // partials ready (also drains prev prefetch)
      const int rl = (m >> 2) * 16 + nl, ri = m & 3;
      float rz = bz, rr2 = brr, rh = bhh;
#pragma unroll
      for (int ww = 0; ww < 4; ++ww) {
        rz += red[ww][0][rl][ri];
        rr2 += red[ww][1][rl][ri];
        rh += red[ww][2][rl][ri];
      }
      const float z = frcp(1.f + __expf(-(xz + rz)));
      const float rg = frcp(1.f + __expf(-(xr + rr2)));
      const float hh = tanhf(xh + rg * rh);
      h = z * h + (1.f - z) * hh;   // h stays f32 locally
      // publish h(t+1): ONE write-through store into hist rows 16(t+1)..
      const unsigned hb16 = (unsigned short)f2bf(h);
      const unsigned nb = __shfl(hb16, lane | 1, 64);
      const unsigned pv = hb16 | (nb << 16);
      if (!(tid & 1))
        __hip_atomic_store(
            (unsigned*)hist + (((size_t)(t + 1) * 16 + m) * 1024 + col) / 2,
            pv, __ATOMIC_RELAXED, __HIP_MEMORY_SCOPE_AGENT);
      __syncthreads();  // drains the h stores -> visible at L3
      if (tid == 0)
        __hip_atomic_store(&scanflag[c * FSTRIDE], (unsigned)(t + 1),
                           __ATOMIC_RELAXED, __HIP_MEMORY_SCOPE_AGENT);
      if ((t & 7) == 7) {  // worker-frontier flag, 1-in-8 steps
        if (tid == 0)
          __hip_atomic_store(&frontier[c * FSTRIDE], (unsigned)(t + 1),
                             __ATOMIC_RELAXED, __HIP_MEMORY_SCOPE_AGENT);
      }
      {  // prefetch next step's x slice (pad rows exist: zero teacher)
        const float* xn = xb + (size_t)(t + 1) * 16 * G_;
        xz = xn[col]; xr = xn[1024 + col]; xh = xn[2048 + col];
      }
      if (t < TSTEPS - 1) {  // poll all 64 scan flags (sc-bypass, self-paced)
        const unsigned* fp = &scanflag[lane * FSTRIDE];
        unsigned v = __hip_atomic_load(fp, __ATOMIC_RELAXED,
                                       __HIP_MEMORY_SCOPE_AGENT);
        while (!__all(v > (unsigned)t))
          v = __hip_atomic_load(fp, __ATOMIC_RELAXED, __HIP_MEMORY_SCOPE_AGENT);
      }
    }
    // epilogue: final h rows already drained (barrier above) -> frontier 256
    if (tid == 0)
      __hip_atomic_store(&frontier[c * FSTRIDE], 256u,
                         __ATOMIC_RELAXED, __HIP_MEMORY_SCOPE_AGENT);
  } else {
    // ================= dense GEMM worker role =================
    char* sb = (char*)smem_v;
    const int wr = w >> 1, wc = w & 1;
    const int xterm = ((q ^ ((r >> 1) & 3)) << 4);              // LDS slot swz
    const int swz8 = (((lane & 3) ^ ((lane >> 3) & 3)) << 3);   // src col swz
    const int j = blockIdx.x - NBLK_SCAN;  // 0..447
#pragma unroll 1
    for (int tq = j; tq < NTILE_RB * NTILE_CB; tq += NWORK) {
      const int rb = tq / NTILE_CB, cb = tq - rb * NTILE_CB;
      const unsigned need = (unsigned)(rb < 31 ? 8 * rb + 8 : 256);
      unsigned v = __hip_atomic_load(&frontier[lane * FSTRIDE], __ATOMIC_RELAXED,
                                     __HIP_MEMORY_SCOPE_AGENT);
      while (!__all(v >= need)) {
        __builtin_amdgcn_s_sleep(32);
        v = __hip_atomic_load(&frontier[lane * FSTRIDE], __ATOMIC_RELAXED,
                              __HIP_MEMORY_SCOPE_AGENT);
      }
      // A from hist rows 16.. (= old gruout rows); normal loads, coherent
      const short* Ag = hist + (size_t)16 * 1024 + (size_t)rb * 128 * 1024;
      const short* Bg = DwT + (size_t)cb * 128 * 1024;
      f32x4 acc[4][4] = {};
#define STAGE(buf, kk)                                                         \
  {                                                                            \
    _Pragma("unroll") for (int it = 0; it < 2; ++it) {                         \
      const size_t go = (size_t)(w * 32 + it * 16 + (lane >> 2)) * 1024 +      \
                        (kk) * 32 + swz8;                                      \
      char* lb2 = sb + (buf) * 16384 + w * 2048 + it * 1024;                   \
      gload_lds16(Ag + go, lb2);                                               \
      gload_lds16(Bg + go, lb2 + 8192);                                        \
    }                                                                          \
  }
      STAGE(0, 0)
#pragma unroll 1
      for (int kk = 0; kk < 32; ++kk) {
        __syncthreads();             // staged kk visible; prev buf reads done
        if (kk < 31) STAGE((kk + 1) & 1, kk + 1)
        const char* ab = sb + (kk & 1) * 16384;
        s16x8 af[4], bf[4];
#pragma unroll
        for (int i = 0; i < 4; ++i)
          af[i] = *(const s16x8*)(ab + (wr * 64 + i * 16 + r) * 64 + xterm);
#pragma unroll
        for (int j5 = 0; j5 < 4; ++j5)
          bf[j5] = *(const s16x8*)(ab + 8192 + (wc * 64 + j5 * 16 + r) * 64 + xterm);
#pragma unroll
        for (int i = 0; i < 4; ++i)
#pragma unroll
          for (int j5 = 0; j5 < 4; ++j5)
            acc[i][j5] = __builtin_amdgcn_mfma_f32_16x16x32_bf16(
                af[i], bf[j5], acc[i][j5], 0, 0, 0);
      }
#undef STAGE
      const int wm = rb * 128 + wr * 64, wn = cb * 128 + wc * 64;
#pragma unroll
      for (int j2 = 0; j2 < 4; ++j2) {
        const int col = wn + j2 * 16 + r;
        const float bv = db[col];
#pragma unroll
        for (int i = 0; i < 4; ++i) {
#pragma unroll
          for (int rr = 0; rr < 4; ++rr) {
            const int arow = wm + i * 16 + q * 4 + rr;
            const int t = arow >> 4, mm = arow & 15;
            if (t < TSTEPS)
              __builtin_nontemporal_store(
                  acc[i][j2][rr] + bv,
                  &out[(size_t)(mm * TSTEPS + t) * V_ + col]);
          }
        }
      }
      __syncthreads();  // LDS WAR: next tile's STAGE(0,0) vs this tile's reads
    }
  }
}

// ---------- launch ----------
extern "C" void kernel_launch(void* const* d_in, const int* in_sizes, int n_in,
                              void* d_out, int out_size, void* d_ws, size_t ws_size,
                              hipStream_t stream) {
  const float* latent = (const float*)d_in[0];
  const float* trueo  = (const float*)d_in[1];
  const float* gk     = (const float*)d_in[2];
  const float* grk    = (const float*)d_in[3];
  const float* gbias  = (const float*)d_in[4];
  const float* dw     = (const float*)d_in[5];
  const float* db     = (const float*)d_in[6];
  float* out = (float*)d_out;
  char* ws = (char*)d_ws;
  short*    WrecT  = (short*)(ws + 0);          //  6,291,456  [3072][1024] bf16
  short*    GkT    = (short*)(ws + 6291456);    //  3,145,728  [3072][512]  bf16
  short*    DwT    = (short*)(ws + 9437184);    // 65,536,000  [32000][1024] bf16
  short*    teachA = (short*)(ws + 74973184);   //  4,194,304  [4096][512]  bf16 rows t*16+b
  float*    xproj  = (float*)(ws + 79167488);   // 50,331,648  [4096][3072] f32 rows t*16+m
  short*    hist   = (short*)(ws + 129499136);  //  8,421,376  [4112][1024] bf16 h-history
  unsigned* syncb  = (unsigned*)(ws + 137920512); //    8,192  scanflags + frontier

  hipMemsetAsync(syncb, 0, 8192, stream);
  transpose_cvt<<<dim3(96, 32), dim3(32, 8), 0, stream>>>(grk, WrecT, 1024, 3072);
  transpose_cvt<<<dim3(96, 16), dim3(32, 8), 0, stream>>>(gk, GkT, 512, 3072);
  transpose_cvt<<<dim3(1000, 32), dim3(32, 8), 0, stream>>>(dw, DwT, 1024, 32000);
  pack_teacher<<<1024, 256, 0, stream>>>(trueo, teachA);
  gemm_bf16<<<dim3(24, 32), 256, 0, stream>>>(teachA, GkT, gbias, xproj, G_, E_);
  init_h<<<64, 256, 0, stream>>>(latent, hist);
  fused_scan_gemm<<<NBLK_TOT, 256, 0, stream>>>(WrecT, xproj, gbias + G_, latent,
                                                hist, DwT, db, out, syncb);
}